// Round 2
// baseline (392.893 us; speedup 1.0000x reference)
//
#include <hip/hip_runtime.h>

// ImageWiseConv2d: per-sample conv, images [64,64,128,128] f32, kernels [64,64,3,3] f32
// out [64,1,126,126] f32 (VALID, stride 1).
//
// R5: occupancy-doubling restructure of the R3 direct-streaming kernel.
// Theory: R3 (~100 us kernel) was latency-bound at 2 waves/SIMD -- prefetch is 1 channel
// deep (~144 VALU cycles of cover) vs ~900-cycle HBM latency, so the outstanding-load
// duty cycle was too low to saturate HBM (ran at ~45% of achievable BW).
// Change: 1x4 outputs/thread (3 input rows, 72 B/channel) instead of 2x4 (4 rows, 96 B),
// 512-thread blocks, same 512-block grid -> 16 waves/CU = 4 waves/SIMD (2x TLP).
// HBM-unique traffic unchanged (~290 MB -> ~46 us floor). Cache-level amplification
// +50% (1.2 GB total) -- well under L1/L2 aggregate BW.
// Register footprint drops (2 buffers x 18 floats + 4 acc + addrs ~= 60 VGPR), so
// __launch_bounds__(512,4) (VGPR cap 128) has ample margin -- no R1/R2-style spill.
// Still: NO LDS, NO barriers, no workspace; weights via wave-uniform s_load.

#define NS   64
#define CCH  64
#define HH   128
#define WW   128
#define OHH  126
#define OWW  126
#define CHS  (HH * WW)   // 16384 floats per channel

__global__ __launch_bounds__(512, 4)
void ImageWiseConv2d_direct(const float* __restrict__ img,
                            const float* __restrict__ ker,
                            float* __restrict__ out)
{
    const int tid = threadIdx.x;
    const int bx  = blockIdx.x;          // 0..511
    const int bt  = bx & 7;              // row tile (16 output rows)
    const int n   = bx >> 3;             // sample
    const int h0  = bt * 16;

    const int r0 = tid >> 5;             // output row within tile: 0..15
    const int c0 = (tid & 31) << 2;      // patch left output col: 0..124

    // input rows ihr..ihr+2; clamp so we never read past row 127.
    // Clamped cases are bt=7, r0=14/15 whose outputs (oh=126/127) are discarded.
    int ihr = h0 + r0;
    if (ihr > HH - 3) ihr = HH - 3;
    // cols c0+4,c0+5 via float2; for c0=124 clamp to cols 126,127 (in-row; values
    // only feed output cols 126/127 which are never stored)
    const int bOff = (c0 < 124) ? 4 : 2;

    const float* p0 = img + (((n * CCH) * HH) + ihr) * WW + c0;
    const float* kp = ker + (n * CCH) * 9;   // block-uniform -> scalar loads

    float a0 = 0.f, a1 = 0.f, a2 = 0.f, a3 = 0.f;

    // current-channel patch registers: 3 rows x (float4 + float2) = 18 floats
    float4 A0, A1, A2;
    float2 B0, B1, B2;
    A0 = *(const float4*)(p0);
    A1 = *(const float4*)(p0 + WW);
    A2 = *(const float4*)(p0 + 2 * WW);
    B0 = *(const float2*)(p0 + bOff);
    B1 = *(const float2*)(p0 + WW + bOff);
    B2 = *(const float2*)(p0 + 2 * WW + bOff);

    for (int c = 0; c < CCH; ++c) {
        // prefetch next channel into fresh registers (no barrier anywhere)
        float4 nA0, nA1, nA2;
        float2 nB0, nB1, nB2;
        const bool more = (c + 1 < CCH);
        if (more) {
            const float* q = p0 + (c + 1) * CHS;
            nA0 = *(const float4*)(q);
            nA1 = *(const float4*)(q + WW);
            nA2 = *(const float4*)(q + 2 * WW);
            nB0 = *(const float2*)(q + bOff);
            nB1 = *(const float2*)(q + WW + bOff);
            nB2 = *(const float2*)(q + 2 * WW + bOff);
        }

        const float w0 = kp[c * 9 + 0], w1 = kp[c * 9 + 1], w2 = kp[c * 9 + 2];
        const float w3 = kp[c * 9 + 3], w4 = kp[c * 9 + 4], w5 = kp[c * 9 + 5];
        const float w6 = kp[c * 9 + 6], w7 = kp[c * 9 + 7], w8 = kp[c * 9 + 8];

        // input row 0 -> kernel row 0
        {
            const float v0 = A0.x, v1 = A0.y, v2 = A0.z, v3 = A0.w, v4 = B0.x, v5 = B0.y;
            a0 = fmaf(w0, v0, a0); a0 = fmaf(w1, v1, a0); a0 = fmaf(w2, v2, a0);
            a1 = fmaf(w0, v1, a1); a1 = fmaf(w1, v2, a1); a1 = fmaf(w2, v3, a1);
            a2 = fmaf(w0, v2, a2); a2 = fmaf(w1, v3, a2); a2 = fmaf(w2, v4, a2);
            a3 = fmaf(w0, v3, a3); a3 = fmaf(w1, v4, a3); a3 = fmaf(w2, v5, a3);
        }
        // input row 1 -> kernel row 1
        {
            const float v0 = A1.x, v1 = A1.y, v2 = A1.z, v3 = A1.w, v4 = B1.x, v5 = B1.y;
            a0 = fmaf(w3, v0, a0); a0 = fmaf(w4, v1, a0); a0 = fmaf(w5, v2, a0);
            a1 = fmaf(w3, v1, a1); a1 = fmaf(w4, v2, a1); a1 = fmaf(w5, v3, a1);
            a2 = fmaf(w3, v2, a2); a2 = fmaf(w4, v3, a2); a2 = fmaf(w5, v4, a2);
            a3 = fmaf(w3, v3, a3); a3 = fmaf(w4, v4, a3); a3 = fmaf(w5, v5, a3);
        }
        // input row 2 -> kernel row 2
        {
            const float v0 = A2.x, v1 = A2.y, v2 = A2.z, v3 = A2.w, v4 = B2.x, v5 = B2.y;
            a0 = fmaf(w6, v0, a0); a0 = fmaf(w7, v1, a0); a0 = fmaf(w8, v2, a0);
            a1 = fmaf(w6, v1, a1); a1 = fmaf(w7, v2, a1); a1 = fmaf(w8, v3, a1);
            a2 = fmaf(w6, v2, a2); a2 = fmaf(w7, v3, a2); a2 = fmaf(w8, v4, a2);
            a3 = fmaf(w6, v3, a3); a3 = fmaf(w7, v4, a3); a3 = fmaf(w8, v5, a3);
        }

        if (more) {
            A0 = nA0; A1 = nA1; A2 = nA2;
            B0 = nB0; B1 = nB1; B2 = nB2;
        }
    }

    // ---- store 1x4 (float2 pairs: out rows are 8B- but not 16B-aligned) ----
    const int oh = h0 + r0;
    if (oh < OHH) {
        float* o0 = out + (n * OHH + oh) * OWW + c0;
        *(float2*)o0 = make_float2(a0, a1);
        if (c0 < 124) {
            *(float2*)(o0 + 2) = make_float2(a2, a3);
        }
    }
}

extern "C" void kernel_launch(void* const* d_in, const int* in_sizes, int n_in,
                              void* d_out, int out_size, void* d_ws, size_t ws_size,
                              hipStream_t stream) {
    const float* img = (const float*)d_in[0];   // [64,64,128,128] f32
    const float* ker = (const float*)d_in[1];   // [64,64,3,3] f32
    float* out = (float*)d_out;                 // [64,1,126,126] f32

    ImageWiseConv2d_direct<<<dim3(NS * 8), dim3(512), 0, stream>>>(img, ker, out);
}

// Round 3
// 354.881 us; speedup vs baseline: 1.1071x; 1.1071x over previous
//
#include <hip/hip_runtime.h>

// ImageWiseConv2d: per-sample conv, images [64,64,128,128] f32, kernels [64,64,3,3] f32
// out [64,1,126,126] f32 (VALID, stride 1).
//
// R6: R3 structure (2x4 outputs/thread, 256 thr, 512 blocks, no LDS/barriers) with the
// float2 halo loads replaced by cross-lane shuffles.
// Evidence: R5 (1x4/thread, 2x waves) REGRESSED 356.7 -> 392.9 us total. Latency theory
// dead; runtime tracks L1-level load traffic (R3 786 MB ~98us, R5 1.18 GB ~135us,
// ~8 TB/s effective aggregate). So: cut load traffic per output.
// The halo cols c0+4,c0+5 of each row are lane+1's A.x,A.y -> __shfl_down(x,1)
// (ds_bpermute, DS pipe, ~10us aggregate, overlapped) instead of 4x float2 VMEM loads.
// Per wave per channel: 4 KB / 4 VMEM instrs (was 6 KB / 8). HBM unchanged (~290 MB).
// Edge safety: lanes with garbage halo (c0=124; lane31->lane32 row leak) only feed
// a02/a03 which are never stored for c0=124.
// Prediction: kernel ~98 -> ~65-75 us, total ~320-335 us.

#define NS   64
#define CCH  64
#define HH   128
#define WW   128
#define OHH  126
#define OWW  126
#define CHS  (HH * WW)   // 16384 floats per channel

__global__ __launch_bounds__(256, 2)
void ImageWiseConv2d_direct(const float* __restrict__ img,
                            const float* __restrict__ ker,
                            float* __restrict__ out)
{
    const int tid = threadIdx.x;
    const int bx  = blockIdx.x;          // 0..511
    const int bt  = bx & 7;              // row tile (16 output rows)
    const int n   = bx >> 3;             // sample
    const int h0  = bt * 16;

    const int r0 = (tid >> 5) << 1;      // patch top output row within tile: 0..14
    const int c0 = (tid & 31) << 2;      // patch left output col: 0..124

    // input rows ihr..ihr+3; clamp so we never read past row 127 (clamped case is
    // bt=7,r0=14 whose outputs are discarded)
    int ihr = h0 + r0;
    if (ihr > HH - 4) ihr = HH - 4;

    const float* p0 = img + (((n * CCH) * HH) + ihr) * WW + c0;
    const float* kp = ker + (n * CCH) * 9;   // block-uniform -> scalar loads

    float a00 = 0.f, a01 = 0.f, a02 = 0.f, a03 = 0.f;
    float a10 = 0.f, a11 = 0.f, a12 = 0.f, a13 = 0.f;

    // current-channel patch registers: 4 rows x float4 (halo via shfl)
    float4 A0, A1, A2, A3;
    A0 = *(const float4*)(p0);
    A1 = *(const float4*)(p0 + WW);
    A2 = *(const float4*)(p0 + 2 * WW);
    A3 = *(const float4*)(p0 + 3 * WW);

    for (int c = 0; c < CCH; ++c) {
        // prefetch next channel into fresh registers (no barrier anywhere)
        float4 nA0, nA1, nA2, nA3;
        const bool more = (c + 1 < CCH);
        if (more) {
            const float* q = p0 + (c + 1) * CHS;
            nA0 = *(const float4*)(q);
            nA1 = *(const float4*)(q + WW);
            nA2 = *(const float4*)(q + 2 * WW);
            nA3 = *(const float4*)(q + 3 * WW);
        }

        const float w0 = kp[c * 9 + 0], w1 = kp[c * 9 + 1], w2 = kp[c * 9 + 2];
        const float w3 = kp[c * 9 + 3], w4 = kp[c * 9 + 4], w5 = kp[c * 9 + 5];
        const float w6 = kp[c * 9 + 6], w7 = kp[c * 9 + 7], w8 = kp[c * 9 + 8];

        // halo values: cols c0+4, c0+5 live in lane+1's A.x, A.y.
        // Garbage for lane 31 within each row-group (crosses into other row / wave end),
        // but those lanes have c0=124 where only a*0/a*1 are stored.
        const float h40 = __shfl_down(A0.x, 1), h50 = __shfl_down(A0.y, 1);
        const float h41 = __shfl_down(A1.x, 1), h51 = __shfl_down(A1.y, 1);
        const float h42 = __shfl_down(A2.x, 1), h52 = __shfl_down(A2.y, 1);
        const float h43 = __shfl_down(A3.x, 1), h53 = __shfl_down(A3.y, 1);

        // row 0 -> acc0 (kernel row 0)
        {
            const float v0 = A0.x, v1 = A0.y, v2 = A0.z, v3 = A0.w, v4 = h40, v5 = h50;
            a00 = fmaf(w0, v0, a00); a00 = fmaf(w1, v1, a00); a00 = fmaf(w2, v2, a00);
            a01 = fmaf(w0, v1, a01); a01 = fmaf(w1, v2, a01); a01 = fmaf(w2, v3, a01);
            a02 = fmaf(w0, v2, a02); a02 = fmaf(w1, v3, a02); a02 = fmaf(w2, v4, a02);
            a03 = fmaf(w0, v3, a03); a03 = fmaf(w1, v4, a03); a03 = fmaf(w2, v5, a03);
        }
        // row 1 -> acc0 (kr 1), acc1 (kr 0)
        {
            const float v0 = A1.x, v1 = A1.y, v2 = A1.z, v3 = A1.w, v4 = h41, v5 = h51;
            a00 = fmaf(w3, v0, a00); a00 = fmaf(w4, v1, a00); a00 = fmaf(w5, v2, a00);
            a01 = fmaf(w3, v1, a01); a01 = fmaf(w4, v2, a01); a01 = fmaf(w5, v3, a01);
            a02 = fmaf(w3, v2, a02); a02 = fmaf(w4, v3, a02); a02 = fmaf(w5, v4, a02);
            a03 = fmaf(w3, v3, a03); a03 = fmaf(w4, v4, a03); a03 = fmaf(w5, v5, a03);
            a10 = fmaf(w0, v0, a10); a10 = fmaf(w1, v1, a10); a10 = fmaf(w2, v2, a10);
            a11 = fmaf(w0, v1, a11); a11 = fmaf(w1, v2, a11); a11 = fmaf(w2, v3, a11);
            a12 = fmaf(w0, v2, a12); a12 = fmaf(w1, v3, a12); a12 = fmaf(w2, v4, a12);
            a13 = fmaf(w0, v3, a13); a13 = fmaf(w1, v4, a13); a13 = fmaf(w2, v5, a13);
        }
        // row 2 -> acc0 (kr 2), acc1 (kr 1)
        {
            const float v0 = A2.x, v1 = A2.y, v2 = A2.z, v3 = A2.w, v4 = h42, v5 = h52;
            a00 = fmaf(w6, v0, a00); a00 = fmaf(w7, v1, a00); a00 = fmaf(w8, v2, a00);
            a01 = fmaf(w6, v1, a01); a01 = fmaf(w7, v2, a01); a01 = fmaf(w8, v3, a01);
            a02 = fmaf(w6, v2, a02); a02 = fmaf(w7, v3, a02); a02 = fmaf(w8, v4, a02);
            a03 = fmaf(w6, v3, a03); a03 = fmaf(w7, v4, a03); a03 = fmaf(w8, v5, a03);
            a10 = fmaf(w3, v0, a10); a10 = fmaf(w4, v1, a10); a10 = fmaf(w5, v2, a10);
            a11 = fmaf(w3, v1, a11); a11 = fmaf(w4, v2, a11); a11 = fmaf(w5, v3, a11);
            a12 = fmaf(w3, v2, a12); a12 = fmaf(w4, v3, a12); a12 = fmaf(w5, v4, a12);
            a13 = fmaf(w3, v3, a13); a13 = fmaf(w4, v4, a13); a13 = fmaf(w5, v5, a13);
        }
        // row 3 -> acc1 (kr 2)
        {
            const float v0 = A3.x, v1 = A3.y, v2 = A3.z, v3 = A3.w, v4 = h43, v5 = h53;
            a10 = fmaf(w6, v0, a10); a10 = fmaf(w7, v1, a10); a10 = fmaf(w8, v2, a10);
            a11 = fmaf(w6, v1, a11); a11 = fmaf(w7, v2, a11); a11 = fmaf(w8, v3, a11);
            a12 = fmaf(w6, v2, a12); a12 = fmaf(w7, v3, a12); a12 = fmaf(w8, v4, a12);
            a13 = fmaf(w6, v3, a13); a13 = fmaf(w7, v4, a13); a13 = fmaf(w8, v5, a13);
        }

        if (more) {
            A0 = nA0; A1 = nA1; A2 = nA2; A3 = nA3;
        }
    }

    // ---- store 2x4 (float2 pairs: out rows are 8B- but not 16B-aligned) ----
    const int oh0 = h0 + r0;
    if (oh0 < OHH) {           // oh0 invalid only for bt=7,r0=14, where oh0+1 is too
        float* o0 = out + (n * OHH + oh0) * OWW + c0;
        float* o1 = o0 + OWW;
        *(float2*)o0 = make_float2(a00, a01);
        *(float2*)o1 = make_float2(a10, a11);
        if (c0 < 124) {
            *(float2*)(o0 + 2) = make_float2(a02, a03);
            *(float2*)(o1 + 2) = make_float2(a12, a13);
        }
    }
}

extern "C" void kernel_launch(void* const* d_in, const int* in_sizes, int n_in,
                              void* d_out, int out_size, void* d_ws, size_t ws_size,
                              hipStream_t stream) {
    const float* img = (const float*)d_in[0];   // [64,64,128,128] f32
    const float* ker = (const float*)d_in[1];   // [64,64,3,3] f32
    float* out = (float*)d_out;                 // [64,1,126,126] f32

    ImageWiseConv2d_direct<<<dim3(NS * 8), dim3(256), 0, stream>>>(img, ker, out);
}